// Round 18
// baseline (182.723 us; speedup 1.0000x reference)
//
#include <hip/hip_runtime.h>
#include <hip/hip_bf16.h>
#include <hip/hip_fp16.h>

// GCN forward: emb-gather -> GCNConv(64->128) -> ReLU -> GCNConv(128->128) -> ReLU
//              -> global_max_pool -> Linear(128->10)
// N=100000, E=600000, VOCAB=5000, G=2000, C=10.
// k_mlp (256 thr / 16 nodes): 8 half-waves x 2 nodes; 16B/lane quad-row gathers
// (one load covers 4 edge rows, shfl_xor reduce) -> LDS -> 4-wave MFMA gemm1(+bias,relu)
// -> LDS -> gemm2(dinv) -> P fp16. Row ranges as int2 (one 8B load per node).
// k_agg2pool: 16B/lane parity gather (one load covers 2 rows), shfl_xor(16) reduce,
// LDS pool consolidation.

typedef _Float16 h8 __attribute__((ext_vector_type(8)));
typedef float f32x4 __attribute__((ext_vector_type(4)));

// Zero deg (n4i int4s) and pool (p4i int4s).
__global__ __launch_bounds__(256) void k_zero(int4* __restrict__ deg, int n4i,
                                              int4* __restrict__ pool, int p4i) {
    int t = blockIdx.x * 256 + threadIdx.x;
    int4 z = make_int4(0, 0, 0, 0);
    if (t < n4i) deg[t] = z;
    if (t < p4i) pool[t] = z;
}

// Fused: [0,gE) degree atomics; [gE,gE+nCast) e16 = fp16(emb); then W1T; then W2T.
__global__ __launch_bounds__(256) void k_degprep(const int* __restrict__ dst, int* __restrict__ deg, int E,
                                                 const float* __restrict__ emb, __half2* __restrict__ e16,
                                                 const float* __restrict__ W1, _Float16* __restrict__ W1T,
                                                 const float* __restrict__ W2, _Float16* __restrict__ W2T,
                                                 int nEmbF, int gE, int nCast) {
    int bid = blockIdx.x;
    if (bid < gE) {
        int e = bid * 256 + threadIdx.x;
        if (e < E) atomicAdd(&deg[dst[e]], 1);
    } else if (bid < gE + nCast) {
        int t = (bid - gE) * 256 + threadIdx.x;  // one thread = 4 floats
        if (t * 4 < nEmbF) {
            float4 v = *(const float4*)&emb[t * 4];
            e16[t * 2] = __floats2half2_rn(v.x, v.y);
            e16[t * 2 + 1] = __floats2half2_rn(v.z, v.w);
        }
    } else if (bid < gE + nCast + 32) {
        int t = (bid - gE - nCast) * 256 + threadIdx.x;  // 128*64
        int c = t >> 6, k = t & 63;
        W1T[c * 64 + k] = (_Float16)W1[k * 128 + c];
    } else {
        int t = (bid - gE - nCast - 32) * 256 + threadIdx.x;  // 128*128
        if (t < 128 * 128) {
            int c = t >> 7, k = t & 127;
            W2T[c * 128 + k] = (_Float16)W2[k * 128 + c];
        }
    }
}

// scan1 + dinv fused: exc = block-local exclusive scan of deg
__global__ __launch_bounds__(256) void k_scan1(const int* __restrict__ deg, int* __restrict__ exc,
                                               int* __restrict__ bsums, float* __restrict__ dinv, int N) {
    __shared__ int s[256];
    int i = blockIdx.x * 256 + threadIdx.x;
    int v = (i < N) ? deg[i] : 0;
    if (i < N) dinv[i] = rsqrtf((float)(v + 1));  // +1 self-loop
    s[threadIdx.x] = v;
    __syncthreads();
    for (int off = 1; off < 256; off <<= 1) {
        int t = (threadIdx.x >= (unsigned)off) ? s[threadIdx.x - off] : 0;
        __syncthreads();
        s[threadIdx.x] += t;
        __syncthreads();
    }
    if (i < N) exc[i] = s[threadIdx.x] - v;
    if (threadIdx.x == 255) bsums[blockIdx.x] = s[255];
}

__global__ __launch_bounds__(512) void k_scan2(int* __restrict__ bsums, int nb) {
    __shared__ int s[512];
    int i = threadIdx.x;
    int v = (i < nb) ? bsums[i] : 0;
    s[i] = v;
    __syncthreads();
    for (int off = 1; off < 512; off <<= 1) {
        int t = (i >= off) ? s[i - off] : 0;
        __syncthreads();
        s[i] += t;
        __syncthreads();
    }
    if (i < nb) bsums[i] = s[i] - v;
}

// scan3: cursor[i] = global rowstart; rse[i] = {start, end} (one 8B load for consumers)
__global__ __launch_bounds__(256) void k_scan3(const int* __restrict__ exc, int* __restrict__ cursor,
                                               const int* __restrict__ bsums, int2* __restrict__ rse,
                                               int N, int E) {
    int i = blockIdx.x * 256 + threadIdx.x;
    if (i < N) {
        int r = exc[i] + bsums[blockIdx.x];
        int rn = (i + 1 < N) ? exc[i + 1] + bsums[(i + 1) >> 8] : E;
        cursor[i] = r;
        rse[i] = make_int2(r, rn);
    }
}

// CSR fill: ed[pos] = {x[src], dinv[src] bits}; cols[pos] = src
__global__ __launch_bounds__(256) void k_fill(const int* __restrict__ src, const int* __restrict__ dst,
                                              const int* __restrict__ x, const float* __restrict__ dinv,
                                              int* __restrict__ cursor, int2* __restrict__ ed,
                                              int* __restrict__ cols, int E) {
    int e = blockIdx.x * 256 + threadIdx.x;
    if (e < E) {
        int d = dst[e];
        int s = src[e];
        int pos = atomicAdd(&cursor[d], 1);
        ed[pos] = make_int2(x[s], __float_as_int(dinv[s]));
        cols[pos] = s;
    }
}

// Fused node pipeline: 256 threads, block = 16 nodes.
// Phase 1: 8 half-waves x 2 nodes. Quad-row gathers: lane=(p=lane>>3, f16=lane&7);
//   one 16B load covers 4 edge rows; f32 accum over 8 feats; shfl_xor(8,16) reduce.
// Phase 2: Hs = relu(Xs @ W1 + b1)   (4 waves: 16 rows x 32 cols each, MFMA)
// Phase 3: P  = dinv * (Hs @ W2)     (same partition, MFMA)
__global__ __launch_bounds__(256) void k_mlp(const __half2* __restrict__ e16, const int* __restrict__ x,
                                             const float* __restrict__ dinv, const int2* __restrict__ rse,
                                             const int2* __restrict__ ed, const _Float16* __restrict__ W1T,
                                             const float* __restrict__ b1, const _Float16* __restrict__ W2T,
                                             _Float16* __restrict__ P, int N) {
    __shared__ _Float16 Xs[16][72];    // 64-dim rows, stride 144B
    __shared__ _Float16 Hs[16][136];   // 128-dim rows, stride 272B
    int tid = threadIdx.x;
    int blk0 = blockIdx.x * 16;
    // ---- Phase 1 ----
    {
        int lane = tid & 31;
        int hw = tid >> 5;   // 0..7
        int p = lane >> 3;   // 0..3 quad
        int f16 = lane & 7;  // h8 slot (8 fp16 feats)
        const h8* e8 = (const h8*)e16;
        int nlA = hw * 2, nlB = nlA + 1;
        int gA = blk0 + nlA; if (gA >= N) gA = N - 1;
        int gB = blk0 + nlB; if (gB >= N) gB = N - 1;
        int2 rA = rse[gA];
        int2 rB = rse[gB];
        int cA0 = rA.x, cA1 = rA.y;
        int cB0 = rB.x, cB1 = rB.y;
        int baseA = (cA0 < cA1) ? cA1 - 1 : 0;
        int baseB = (cB0 < cB1) ? cB1 - 1 : 0;
        float dA = dinv[gA], dB = dinv[gB];
        h8 selfA = e8[(size_t)x[gA] * 8 + f16];
        h8 selfB = e8[(size_t)x[gB] * 8 + f16];
        float accA[8] = {}, accB[8] = {};
        // first batches of A and B issued together: 16 rows in flight
        {
            int eA0 = cA0 + p, eA1 = cA0 + 4 + p;
            int eB0 = cB0 + p, eB1 = cB0 + 4 + p;
            int2 rA0 = ed[(eA0 < cA1) ? eA0 : baseA];
            int2 rA1 = ed[(eA1 < cA1) ? eA1 : baseA];
            int2 rB0 = ed[(eB0 < cB1) ? eB0 : baseB];
            int2 rB1 = ed[(eB1 < cB1) ? eB1 : baseB];
            h8 tA0 = e8[(size_t)rA0.x * 8 + f16];
            h8 tA1 = e8[(size_t)rA1.x * 8 + f16];
            h8 tB0 = e8[(size_t)rB0.x * 8 + f16];
            h8 tB1 = e8[(size_t)rB1.x * 8 + f16];
            float wA0 = (eA0 < cA1) ? __int_as_float(rA0.y) : 0.f;
            float wA1 = (eA1 < cA1) ? __int_as_float(rA1.y) : 0.f;
            float wB0 = (eB0 < cB1) ? __int_as_float(rB0.y) : 0.f;
            float wB1 = (eB1 < cB1) ? __int_as_float(rB1.y) : 0.f;
#pragma unroll
            for (int f = 0; f < 8; ++f) {
                accA[f] = fmaf(wA1, (float)tA1[f], fmaf(wA0, (float)tA0[f], accA[f]));
                accB[f] = fmaf(wB1, (float)tB1[f], fmaf(wB0, (float)tB0[f], accB[f]));
            }
        }
        // tails (deg > 8)
        for (int eb = cA0 + 8; eb < cA1; eb += 8) {
            int e0 = eb + p, e1i = eb + 4 + p;
            int2 r0 = ed[(e0 < cA1) ? e0 : cA1 - 1];
            int2 r1 = ed[(e1i < cA1) ? e1i : cA1 - 1];
            h8 t0 = e8[(size_t)r0.x * 8 + f16];
            h8 t1 = e8[(size_t)r1.x * 8 + f16];
            float w0 = (e0 < cA1) ? __int_as_float(r0.y) : 0.f;
            float w1 = (e1i < cA1) ? __int_as_float(r1.y) : 0.f;
#pragma unroll
            for (int f = 0; f < 8; ++f)
                accA[f] = fmaf(w1, (float)t1[f], fmaf(w0, (float)t0[f], accA[f]));
        }
        for (int eb = cB0 + 8; eb < cB1; eb += 8) {
            int e0 = eb + p, e1i = eb + 4 + p;
            int2 r0 = ed[(e0 < cB1) ? e0 : cB1 - 1];
            int2 r1 = ed[(e1i < cB1) ? e1i : cB1 - 1];
            h8 t0 = e8[(size_t)r0.x * 8 + f16];
            h8 t1 = e8[(size_t)r1.x * 8 + f16];
            float w0 = (e0 < cB1) ? __int_as_float(r0.y) : 0.f;
            float w1 = (e1i < cB1) ? __int_as_float(r1.y) : 0.f;
#pragma unroll
            for (int f = 0; f < 8; ++f)
                accB[f] = fmaf(w1, (float)t1[f], fmaf(w0, (float)t0[f], accB[f]));
        }
        // cross-quad reduce + self + scale, p==0 writes
        h8 yA, yB;
#pragma unroll
        for (int f = 0; f < 8; ++f) {
            float a = accA[f];
            a += __shfl_xor(a, 8);
            a += __shfl_xor(a, 16);
            float b = accB[f];
            b += __shfl_xor(b, 8);
            b += __shfl_xor(b, 16);
            yA[f] = (_Float16)(dA * fmaf(dA, (float)selfA[f], a));
            yB[f] = (_Float16)(dB * fmaf(dB, (float)selfB[f], b));
        }
        if (p == 0) {
            *(h8*)&Xs[nlA][f16 * 8] = yA;
            *(h8*)&Xs[nlB][f16 * 8] = yB;
        }
    }
    __syncthreads();
    int l = tid & 63, wid = tid >> 6;    // 4 waves
    int r = l & 15, kg = l >> 4;
    int ch = wid;                        // col quarter: 32 cols
    // ---- Phase 2: Hs = relu(Xs @ W1 + b1), wave = 16 rows x 32 cols ----
    {
        f32x4 acc[2];
#pragma unroll
        for (int ct = 0; ct < 2; ++ct) acc[ct] = (f32x4){0.f, 0.f, 0.f, 0.f};
#pragma unroll
        for (int kc = 0; kc < 2; ++kc) {
            h8 a = *(const h8*)&Xs[r][kc * 32 + kg * 8];
#pragma unroll
            for (int ct = 0; ct < 2; ++ct) {
                h8 b = *(const h8*)(W1T + (size_t)(ch * 32 + ct * 16 + r) * 64 + kc * 32 + kg * 8);
                acc[ct] = __builtin_amdgcn_mfma_f32_16x16x32_f16(a, b, acc[ct], 0, 0, 0);
            }
        }
#pragma unroll
        for (int ct = 0; ct < 2; ++ct) {
            float bias = b1[ch * 32 + ct * 16 + r];
#pragma unroll
            for (int i = 0; i < 4; ++i)
                Hs[4 * kg + i][ch * 32 + ct * 16 + r] = (_Float16)fmaxf(acc[ct][i] + bias, 0.f);
        }
    }
    __syncthreads();
    // ---- Phase 3: P = dinv * (Hs @ W2), wave = 16 rows x 32 cols ----
    {
        f32x4 acc[2];
#pragma unroll
        for (int ct = 0; ct < 2; ++ct) acc[ct] = (f32x4){0.f, 0.f, 0.f, 0.f};
#pragma unroll
        for (int kc = 0; kc < 4; ++kc) {
            h8 a = *(const h8*)&Hs[r][kc * 32 + kg * 8];
#pragma unroll
            for (int ct = 0; ct < 2; ++ct) {
                h8 b = *(const h8*)(W2T + (size_t)(ch * 32 + ct * 16 + r) * 128 + kc * 32 + kg * 8);
                acc[ct] = __builtin_amdgcn_mfma_f32_16x16x32_f16(a, b, acc[ct], 0, 0, 0);
            }
        }
        float dv[4];
#pragma unroll
        for (int i = 0; i < 4; ++i) {
            int gr = blk0 + 4 * kg + i;
            dv[i] = (gr < N) ? dinv[gr] : 0.f;
        }
#pragma unroll
        for (int ct = 0; ct < 2; ++ct) {
#pragma unroll
            for (int i = 0; i < 4; ++i) {
                int gr = blk0 + 4 * kg + i;
                if (gr < N)
                    P[(size_t)gr * 128 + ch * 32 + ct * 16 + r] = (_Float16)(acc[ct][i] * dv[i]);
            }
        }
    }
}

// Layer-2 + global_max_pool. 256-thr block = 8 half-waves x 2 nodes = 16 sorted nodes.
// 16B/lane parity gather: lane=(p=lane>>4, s=lane&15); one h8 load covers 2 edge rows;
// per-node 16-edge batch = 8 loads/lane; shfl_xor(16) cross-parity reduce; self added
// post-reduce. p==0 emits. LDS pool slots + one global emit per (block,graph,feature).
__global__ __launch_bounds__(256) void k_agg2pool(const h8* __restrict__ P8, const int* __restrict__ batch,
                                                  const float* __restrict__ dinv, const int2* __restrict__ rse,
                                                  const int* __restrict__ cols, const float* __restrict__ b2,
                                                  float* __restrict__ pool, int N, int G) {
    __shared__ int lpool[4][128];
    int tid = threadIdx.x;
    lpool[tid >> 7][tid & 127] = 0;
    lpool[(tid >> 7) + 2][tid & 127] = 0;
    __syncthreads();
    int lane = tid & 31;
    int p = lane >> 4;   // parity (edge subset)
    int s = lane & 15;   // h8 slot: feats s*8..s*8+7
    int blk_n0 = blockIdx.x * 16;
    int gfirst = batch[(blk_n0 < N) ? blk_n0 : (N - 1)];
    int n0 = blk_n0 + (tid >> 5) * 2;
    if (n0 < N) {
        int nA = n0;
        int nB = (n0 + 1 < N) ? n0 + 1 : n0;
        int2 rA = rse[nA];
        int2 rB = rse[nB];
        int cA0 = rA.x, cA1 = rA.y;
        int cB0 = rB.x, cB1 = rB.y;
        bool hasA = cA0 < cA1, hasB = cB0 < cB1;
        h8 sA = P8[(size_t)nA * 16 + s];
        h8 sB = P8[(size_t)nB * 16 + s];
        float aA[8] = {}, aB[8] = {};
        // first 16-edge batches of A and B, dual-issued (8 loads/lane each)
        {
            h8 tA[8], tB[8];
            float wA[8], wB[8];
#pragma unroll
            for (int i = 0; i < 8; ++i) {
                int ei = cA0 + 2 * i + p;
                int ec = (ei < cA1) ? ei : (hasA ? cA1 - 1 : 0);
                tA[i] = P8[(size_t)cols[ec] * 16 + s];
                wA[i] = (ei < cA1) ? 1.f : 0.f;
            }
#pragma unroll
            for (int i = 0; i < 8; ++i) {
                int ei = cB0 + 2 * i + p;
                int ec = (ei < cB1) ? ei : (hasB ? cB1 - 1 : 0);
                tB[i] = P8[(size_t)cols[ec] * 16 + s];
                wB[i] = (ei < cB1) ? 1.f : 0.f;
            }
#pragma unroll
            for (int i = 0; i < 8; ++i)
#pragma unroll
                for (int f = 0; f < 8; ++f) aA[f] = fmaf(wA[i], (float)tA[i][f], aA[f]);
#pragma unroll
            for (int i = 0; i < 8; ++i)
#pragma unroll
                for (int f = 0; f < 8; ++f) aB[f] = fmaf(wB[i], (float)tB[i][f], aB[f]);
        }
        // tails (deg > 16)
        for (int eb = cA0 + 16; eb < cA1; eb += 16) {
            h8 t[8];
            float w[8];
#pragma unroll
            for (int i = 0; i < 8; ++i) {
                int ei = eb + 2 * i + p;
                int ec = (ei < cA1) ? ei : cA1 - 1;
                t[i] = P8[(size_t)cols[ec] * 16 + s];
                w[i] = (ei < cA1) ? 1.f : 0.f;
            }
#pragma unroll
            for (int i = 0; i < 8; ++i)
#pragma unroll
                for (int f = 0; f < 8; ++f) aA[f] = fmaf(w[i], (float)t[i][f], aA[f]);
        }
        for (int eb = cB0 + 16; eb < cB1; eb += 16) {
            h8 t[8];
            float w[8];
#pragma unroll
            for (int i = 0; i < 8; ++i) {
                int ei = eb + 2 * i + p;
                int ec = (ei < cB1) ? ei : cB1 - 1;
                t[i] = P8[(size_t)cols[ec] * 16 + s];
                w[i] = (ei < cB1) ? 1.f : 0.f;
            }
#pragma unroll
            for (int i = 0; i < 8; ++i)
#pragma unroll
                for (int f = 0; f < 8; ++f) aB[f] = fmaf(w[i], (float)t[i][f], aB[f]);
        }
        // cross-parity reduce, then self + bias + relu
        float dA = dinv[nA], dB = dinv[nB];
        int gA = batch[nA], gB = batch[nB];
        float4 bb0 = *(const float4*)&b2[s * 8];
        float4 bb1 = *(const float4*)&b2[s * 8 + 4];
        float bv[8] = {bb0.x, bb0.y, bb0.z, bb0.w, bb1.x, bb1.y, bb1.z, bb1.w};
        float zA[8], zB[8];
#pragma unroll
        for (int f = 0; f < 8; ++f) {
            float a = aA[f] + __shfl_xor(aA[f], 16);
            float b = aB[f] + __shfl_xor(aB[f], 16);
            zA[f] = fmaxf(fmaf(dA, (float)sA[f] + a, bv[f]), 0.f);
            zB[f] = fmaxf(fmaf(dB, (float)sB[f] + b, bv[f]), 0.f);
        }
        auto emit = [&](int g, const float* m) {
            if (p != 0) return;  // parities hold identical values post-reduce
            int slot = g - gfirst;
            if (slot < 4) {
#pragma unroll
                for (int f = 0; f < 8; ++f) {
                    int ff = (f + s) & 7;  // bank rotation
                    if (m[ff] > 0.f) atomicMax(&lpool[slot][s * 8 + ff], __float_as_int(m[ff]));
                }
            } else {
                float* pg = pool + (size_t)g * 128 + s * 8;
#pragma unroll
                for (int f = 0; f < 8; ++f)
                    if (m[f] > 0.f) atomicMax((int*)(pg + f), __float_as_int(m[f]));
            }
        };
        if (gA == gB) {
            float m[8];
#pragma unroll
            for (int f = 0; f < 8; ++f) m[f] = fmaxf(zA[f], zB[f]);
            emit(gA, m);
        } else {
            emit(gA, zA);
            emit(gB, zB);
        }
    }
    __syncthreads();
    {
        int f = tid & 127;
        for (int sl = tid >> 7; sl < 4; sl += 2) {
            int v = lpool[sl][f];
            if (v > 0) atomicMax((int*)&pool[(size_t)(gfirst + sl) * 128 + f], v);
        }
    }
}

// out[g][c] = blin[c] + sum_f pool[g][f] * Wlin[f][c]
__global__ __launch_bounds__(256) void k_final(const float* __restrict__ pool, const float* __restrict__ Wlin,
                                               const float* __restrict__ blin, float* __restrict__ out, int G) {
    int t = blockIdx.x * 256 + threadIdx.x;
    if (t >= G * 10) return;
    int g = t / 10, c = t % 10;
    float acc = blin[c];
    const float* pr = pool + (size_t)g * 128;
#pragma unroll 8
    for (int f = 0; f < 128; ++f) acc = fmaf(pr[f], Wlin[f * 10 + c], acc);
    out[t] = acc;
}

extern "C" void kernel_launch(void* const* d_in, const int* in_sizes, int n_in,
                              void* d_out, int out_size, void* d_ws, size_t ws_size,
                              hipStream_t stream) {
    const int* x = (const int*)d_in[0];
    const int* ei = (const int*)d_in[1];
    const int* batch = (const int*)d_in[2];
    const float* emb = (const float*)d_in[4];
    const float* W1 = (const float*)d_in[5];
    const float* b1 = (const float*)d_in[6];
    const float* W2 = (const float*)d_in[7];
    const float* b2 = (const float*)d_in[8];
    const float* Wlin = (const float*)d_in[9];
    const float* blin = (const float*)d_in[10];
    float* out = (float*)d_out;

    int N = in_sizes[0];
    int E = in_sizes[1] / 2;
    int VOCAB = in_sizes[4] / 64;
    int G = out_size / 10;
    const int* srcp = ei;
    const int* dstp = ei + E;

    char* p = (char*)d_ws;
    auto alloc = [&](size_t bytes) -> char* {
        char* r = p;
        p += (bytes + 255) & ~(size_t)255;
        return r;
    };
    int* deg = (int*)alloc((size_t)N * 4);
    int* exc = (int*)alloc((size_t)N * 4);
    int* cursor = (int*)alloc((size_t)N * 4);
    int2* rse = (int2*)alloc((size_t)N * 8);
    int* bsums = (int*)alloc(512 * 4);
    float* dinv = (float*)alloc((size_t)N * 4);
    int2* ed = (int2*)alloc((size_t)E * 8);
    int* cols = (int*)alloc((size_t)E * 4);
    _Float16* e16 = (_Float16*)alloc((size_t)VOCAB * 64 * 2);
    _Float16* W1T = (_Float16*)alloc(128 * 64 * 2);
    _Float16* W2T = (_Float16*)alloc(128 * 128 * 2);
    _Float16* P = (_Float16*)alloc((size_t)N * 128 * 2);
    float* pool = (float*)alloc((size_t)G * 128 * 4);

    int gE = (E + 255) / 256;
    int gN = (N + 255) / 256;  // 391 <= 512 (scan2 capacity)
    int nEmbF = VOCAB * 64;
    int nCast = (nEmbF / 4 + 255) / 256;

    int n4i = N / 4, p4i = G * 128 / 4;
    int zg = ((n4i > p4i ? n4i : p4i) + 255) / 256;
    k_zero<<<zg, 256, 0, stream>>>((int4*)deg, n4i, (int4*)pool, p4i);
    k_degprep<<<gE + nCast + 32 + 64, 256, 0, stream>>>(dstp, deg, E, emb, (__half2*)e16, W1, W1T,
                                                        W2, W2T, nEmbF, gE, nCast);
    k_scan1<<<gN, 256, 0, stream>>>(deg, exc, bsums, dinv, N);
    k_scan2<<<1, 512, 0, stream>>>(bsums, gN);
    k_scan3<<<gN, 256, 0, stream>>>(exc, cursor, bsums, rse, N, E);
    k_fill<<<gE, 256, 0, stream>>>(srcp, dstp, x, dinv, cursor, ed, cols, E);
    k_mlp<<<(N + 15) / 16, 256, 0, stream>>>((const __half2*)e16, x, dinv, rse, ed, W1T, b1,
                                             W2T, P, N);
    k_agg2pool<<<(N + 15) / 16, 256, 0, stream>>>((const h8*)P, batch, dinv, rse, cols,
                                                  b2, pool, N, G);
    k_final<<<(G * 10 + 255) / 256, 256, 0, stream>>>(pool, Wlin, blin, out, G);
}

// Round 19
// 179.554 us; speedup vs baseline: 1.0176x; 1.0176x over previous
//
#include <hip/hip_runtime.h>
#include <hip/hip_bf16.h>
#include <hip/hip_fp16.h>

// GCN forward: emb-gather -> GCNConv(64->128) -> ReLU -> GCNConv(128->128) -> ReLU
//              -> global_max_pool -> Linear(128->10)
// N=100000, E=600000, VOCAB=5000, G=2000, C=10.
// Packed edge record (8B): ed = { x[src]<<17 | src , dinv[src] bits } — single scattered
// store in fill; serves both k_mlp (x via >>17) and k_agg2pool (src via &0x1FFFF).
// k_mlp (256 thr / 16 nodes): quad-row 16B/lane gathers + shfl reduce -> LDS -> MFMA
// gemm1 -> LDS -> gemm2 -> P fp16. k_agg2pool: parity 16B/lane gather + LDS pool.

typedef _Float16 h8 __attribute__((ext_vector_type(8)));
typedef float f32x4 __attribute__((ext_vector_type(4)));
#define SRCMASK 0x1FFFF

// Zero deg (n4i int4s) and pool (p4i int4s).
__global__ __launch_bounds__(256) void k_zero(int4* __restrict__ deg, int n4i,
                                              int4* __restrict__ pool, int p4i) {
    int t = blockIdx.x * 256 + threadIdx.x;
    int4 z = make_int4(0, 0, 0, 0);
    if (t < n4i) deg[t] = z;
    if (t < p4i) pool[t] = z;
}

// Fused: [0,gE) degree atomics; [gE,gE+nCast) e16 = fp16(emb); then W1T; then W2T.
__global__ __launch_bounds__(256) void k_degprep(const int* __restrict__ dst, int* __restrict__ deg, int E,
                                                 const float* __restrict__ emb, __half2* __restrict__ e16,
                                                 const float* __restrict__ W1, _Float16* __restrict__ W1T,
                                                 const float* __restrict__ W2, _Float16* __restrict__ W2T,
                                                 int nEmbF, int gE, int nCast) {
    int bid = blockIdx.x;
    if (bid < gE) {
        int e = bid * 256 + threadIdx.x;
        if (e < E) atomicAdd(&deg[dst[e]], 1);
    } else if (bid < gE + nCast) {
        int t = (bid - gE) * 256 + threadIdx.x;  // one thread = 4 floats
        if (t * 4 < nEmbF) {
            float4 v = *(const float4*)&emb[t * 4];
            e16[t * 2] = __floats2half2_rn(v.x, v.y);
            e16[t * 2 + 1] = __floats2half2_rn(v.z, v.w);
        }
    } else if (bid < gE + nCast + 32) {
        int t = (bid - gE - nCast) * 256 + threadIdx.x;  // 128*64
        int c = t >> 6, k = t & 63;
        W1T[c * 64 + k] = (_Float16)W1[k * 128 + c];
    } else {
        int t = (bid - gE - nCast - 32) * 256 + threadIdx.x;  // 128*128
        if (t < 128 * 128) {
            int c = t >> 7, k = t & 127;
            W2T[c * 128 + k] = (_Float16)W2[k * 128 + c];
        }
    }
}

// scan1 + dinv fused: exc = block-local exclusive scan of deg
__global__ __launch_bounds__(256) void k_scan1(const int* __restrict__ deg, int* __restrict__ exc,
                                               int* __restrict__ bsums, float* __restrict__ dinv, int N) {
    __shared__ int s[256];
    int i = blockIdx.x * 256 + threadIdx.x;
    int v = (i < N) ? deg[i] : 0;
    if (i < N) dinv[i] = rsqrtf((float)(v + 1));  // +1 self-loop
    s[threadIdx.x] = v;
    __syncthreads();
    for (int off = 1; off < 256; off <<= 1) {
        int t = (threadIdx.x >= (unsigned)off) ? s[threadIdx.x - off] : 0;
        __syncthreads();
        s[threadIdx.x] += t;
        __syncthreads();
    }
    if (i < N) exc[i] = s[threadIdx.x] - v;
    if (threadIdx.x == 255) bsums[blockIdx.x] = s[255];
}

__global__ __launch_bounds__(512) void k_scan2(int* __restrict__ bsums, int nb) {
    __shared__ int s[512];
    int i = threadIdx.x;
    int v = (i < nb) ? bsums[i] : 0;
    s[i] = v;
    __syncthreads();
    for (int off = 1; off < 512; off <<= 1) {
        int t = (i >= off) ? s[i - off] : 0;
        __syncthreads();
        s[i] += t;
        __syncthreads();
    }
    if (i < nb) bsums[i] = s[i] - v;
}

// scan3: cursor[i] = global rowstart; rse[i] = {start, end} (one 8B load for consumers)
__global__ __launch_bounds__(256) void k_scan3(const int* __restrict__ exc, int* __restrict__ cursor,
                                               const int* __restrict__ bsums, int2* __restrict__ rse,
                                               int N, int E) {
    int i = blockIdx.x * 256 + threadIdx.x;
    if (i < N) {
        int r = exc[i] + bsums[blockIdx.x];
        int rn = (i + 1 < N) ? exc[i + 1] + bsums[(i + 1) >> 8] : E;
        cursor[i] = r;
        rse[i] = make_int2(r, rn);
    }
}

// CSR fill: ed[pos] = { x[src]<<17 | src , dinv[src] bits } — ONE 8B scattered store.
__global__ __launch_bounds__(256) void k_fill(const int* __restrict__ src, const int* __restrict__ dst,
                                              const int* __restrict__ x, const float* __restrict__ dinv,
                                              int* __restrict__ cursor, int2* __restrict__ ed, int E) {
    int e = blockIdx.x * 256 + threadIdx.x;
    if (e < E) {
        int d = dst[e];
        int s = src[e];
        int pos = atomicAdd(&cursor[d], 1);
        ed[pos] = make_int2((x[s] << 17) | s, __float_as_int(dinv[s]));
    }
}

// Fused node pipeline: 256 threads, block = 16 nodes.
// Phase 1: 8 half-waves x 2 nodes. Quad-row gathers: lane=(p=lane>>3, f16=lane&7);
//   one 16B load covers 4 edge rows; f32 accum over 8 feats; shfl_xor(8,16) reduce.
// Phase 2: Hs = relu(Xs @ W1 + b1)   (4 waves: 16 rows x 32 cols each, MFMA)
// Phase 3: P  = dinv * (Hs @ W2)     (same partition, MFMA)
__global__ __launch_bounds__(256) void k_mlp(const __half2* __restrict__ e16, const int* __restrict__ x,
                                             const float* __restrict__ dinv, const int2* __restrict__ rse,
                                             const int2* __restrict__ ed, const _Float16* __restrict__ W1T,
                                             const float* __restrict__ b1, const _Float16* __restrict__ W2T,
                                             _Float16* __restrict__ P, int N) {
    __shared__ _Float16 Xs[16][72];    // 64-dim rows, stride 144B
    __shared__ _Float16 Hs[16][136];   // 128-dim rows, stride 272B
    int tid = threadIdx.x;
    int blk0 = blockIdx.x * 16;
    // ---- Phase 1 ----
    {
        int lane = tid & 31;
        int hw = tid >> 5;   // 0..7
        int p = lane >> 3;   // 0..3 quad
        int f16 = lane & 7;  // h8 slot (8 fp16 feats)
        const h8* e8 = (const h8*)e16;
        int nlA = hw * 2, nlB = nlA + 1;
        int gA = blk0 + nlA; if (gA >= N) gA = N - 1;
        int gB = blk0 + nlB; if (gB >= N) gB = N - 1;
        int2 rA = rse[gA];
        int2 rB = rse[gB];
        int cA0 = rA.x, cA1 = rA.y;
        int cB0 = rB.x, cB1 = rB.y;
        int baseA = (cA0 < cA1) ? cA1 - 1 : 0;
        int baseB = (cB0 < cB1) ? cB1 - 1 : 0;
        float dA = dinv[gA], dB = dinv[gB];
        h8 selfA = e8[(size_t)x[gA] * 8 + f16];
        h8 selfB = e8[(size_t)x[gB] * 8 + f16];
        float accA[8] = {}, accB[8] = {};
        // first batches of A and B issued together: 16 rows in flight
        {
            int eA0 = cA0 + p, eA1 = cA0 + 4 + p;
            int eB0 = cB0 + p, eB1 = cB0 + 4 + p;
            int2 rA0 = ed[(eA0 < cA1) ? eA0 : baseA];
            int2 rA1 = ed[(eA1 < cA1) ? eA1 : baseA];
            int2 rB0 = ed[(eB0 < cB1) ? eB0 : baseB];
            int2 rB1 = ed[(eB1 < cB1) ? eB1 : baseB];
            h8 tA0 = e8[(size_t)((unsigned)rA0.x >> 17) * 8 + f16];
            h8 tA1 = e8[(size_t)((unsigned)rA1.x >> 17) * 8 + f16];
            h8 tB0 = e8[(size_t)((unsigned)rB0.x >> 17) * 8 + f16];
            h8 tB1 = e8[(size_t)((unsigned)rB1.x >> 17) * 8 + f16];
            float wA0 = (eA0 < cA1) ? __int_as_float(rA0.y) : 0.f;
            float wA1 = (eA1 < cA1) ? __int_as_float(rA1.y) : 0.f;
            float wB0 = (eB0 < cB1) ? __int_as_float(rB0.y) : 0.f;
            float wB1 = (eB1 < cB1) ? __int_as_float(rB1.y) : 0.f;
#pragma unroll
            for (int f = 0; f < 8; ++f) {
                accA[f] = fmaf(wA1, (float)tA1[f], fmaf(wA0, (float)tA0[f], accA[f]));
                accB[f] = fmaf(wB1, (float)tB1[f], fmaf(wB0, (float)tB0[f], accB[f]));
            }
        }
        // tails (deg > 8)
        for (int eb = cA0 + 8; eb < cA1; eb += 8) {
            int e0 = eb + p, e1i = eb + 4 + p;
            int2 r0 = ed[(e0 < cA1) ? e0 : cA1 - 1];
            int2 r1 = ed[(e1i < cA1) ? e1i : cA1 - 1];
            h8 t0 = e8[(size_t)((unsigned)r0.x >> 17) * 8 + f16];
            h8 t1 = e8[(size_t)((unsigned)r1.x >> 17) * 8 + f16];
            float w0 = (e0 < cA1) ? __int_as_float(r0.y) : 0.f;
            float w1 = (e1i < cA1) ? __int_as_float(r1.y) : 0.f;
#pragma unroll
            for (int f = 0; f < 8; ++f)
                accA[f] = fmaf(w1, (float)t1[f], fmaf(w0, (float)t0[f], accA[f]));
        }
        for (int eb = cB0 + 8; eb < cB1; eb += 8) {
            int e0 = eb + p, e1i = eb + 4 + p;
            int2 r0 = ed[(e0 < cB1) ? e0 : cB1 - 1];
            int2 r1 = ed[(e1i < cB1) ? e1i : cB1 - 1];
            h8 t0 = e8[(size_t)((unsigned)r0.x >> 17) * 8 + f16];
            h8 t1 = e8[(size_t)((unsigned)r1.x >> 17) * 8 + f16];
            float w0 = (e0 < cB1) ? __int_as_float(r0.y) : 0.f;
            float w1 = (e1i < cB1) ? __int_as_float(r1.y) : 0.f;
#pragma unroll
            for (int f = 0; f < 8; ++f)
                accB[f] = fmaf(w1, (float)t1[f], fmaf(w0, (float)t0[f], accB[f]));
        }
        // cross-quad reduce + self + scale, p==0 writes
        h8 yA, yB;
#pragma unroll
        for (int f = 0; f < 8; ++f) {
            float a = accA[f];
            a += __shfl_xor(a, 8);
            a += __shfl_xor(a, 16);
            float b = accB[f];
            b += __shfl_xor(b, 8);
            b += __shfl_xor(b, 16);
            yA[f] = (_Float16)(dA * fmaf(dA, (float)selfA[f], a));
            yB[f] = (_Float16)(dB * fmaf(dB, (float)selfB[f], b));
        }
        if (p == 0) {
            *(h8*)&Xs[nlA][f16 * 8] = yA;
            *(h8*)&Xs[nlB][f16 * 8] = yB;
        }
    }
    __syncthreads();
    int l = tid & 63, wid = tid >> 6;    // 4 waves
    int r = l & 15, kg = l >> 4;
    int ch = wid;                        // col quarter: 32 cols
    // ---- Phase 2: Hs = relu(Xs @ W1 + b1), wave = 16 rows x 32 cols ----
    {
        f32x4 acc[2];
#pragma unroll
        for (int ct = 0; ct < 2; ++ct) acc[ct] = (f32x4){0.f, 0.f, 0.f, 0.f};
#pragma unroll
        for (int kc = 0; kc < 2; ++kc) {
            h8 a = *(const h8*)&Xs[r][kc * 32 + kg * 8];
#pragma unroll
            for (int ct = 0; ct < 2; ++ct) {
                h8 b = *(const h8*)(W1T + (size_t)(ch * 32 + ct * 16 + r) * 64 + kc * 32 + kg * 8);
                acc[ct] = __builtin_amdgcn_mfma_f32_16x16x32_f16(a, b, acc[ct], 0, 0, 0);
            }
        }
#pragma unroll
        for (int ct = 0; ct < 2; ++ct) {
            float bias = b1[ch * 32 + ct * 16 + r];
#pragma unroll
            for (int i = 0; i < 4; ++i)
                Hs[4 * kg + i][ch * 32 + ct * 16 + r] = (_Float16)fmaxf(acc[ct][i] + bias, 0.f);
        }
    }
    __syncthreads();
    // ---- Phase 3: P = dinv * (Hs @ W2), wave = 16 rows x 32 cols ----
    {
        f32x4 acc[2];
#pragma unroll
        for (int ct = 0; ct < 2; ++ct) acc[ct] = (f32x4){0.f, 0.f, 0.f, 0.f};
#pragma unroll
        for (int kc = 0; kc < 4; ++kc) {
            h8 a = *(const h8*)&Hs[r][kc * 32 + kg * 8];
#pragma unroll
            for (int ct = 0; ct < 2; ++ct) {
                h8 b = *(const h8*)(W2T + (size_t)(ch * 32 + ct * 16 + r) * 128 + kc * 32 + kg * 8);
                acc[ct] = __builtin_amdgcn_mfma_f32_16x16x32_f16(a, b, acc[ct], 0, 0, 0);
            }
        }
        float dv[4];
#pragma unroll
        for (int i = 0; i < 4; ++i) {
            int gr = blk0 + 4 * kg + i;
            dv[i] = (gr < N) ? dinv[gr] : 0.f;
        }
#pragma unroll
        for (int ct = 0; ct < 2; ++ct) {
#pragma unroll
            for (int i = 0; i < 4; ++i) {
                int gr = blk0 + 4 * kg + i;
                if (gr < N)
                    P[(size_t)gr * 128 + ch * 32 + ct * 16 + r] = (_Float16)(acc[ct][i] * dv[i]);
            }
        }
    }
}

// Layer-2 + global_max_pool. 256-thr block = 8 half-waves x 2 nodes = 16 sorted nodes.
// 16B/lane parity gather: lane=(p=lane>>4, s=lane&15); one h8 load covers 2 edge rows;
// shfl_xor(16) cross-parity reduce; self added post-reduce. p==0 emits. LDS pool slots.
__global__ __launch_bounds__(256) void k_agg2pool(const h8* __restrict__ P8, const int* __restrict__ batch,
                                                  const float* __restrict__ dinv, const int2* __restrict__ rse,
                                                  const int2* __restrict__ ed, const float* __restrict__ b2,
                                                  float* __restrict__ pool, int N, int G) {
    __shared__ int lpool[4][128];
    int tid = threadIdx.x;
    lpool[tid >> 7][tid & 127] = 0;
    lpool[(tid >> 7) + 2][tid & 127] = 0;
    __syncthreads();
    int lane = tid & 31;
    int p = lane >> 4;   // parity (edge subset)
    int s = lane & 15;   // h8 slot: feats s*8..s*8+7
    int blk_n0 = blockIdx.x * 16;
    int gfirst = batch[(blk_n0 < N) ? blk_n0 : (N - 1)];
    int n0 = blk_n0 + (tid >> 5) * 2;
    if (n0 < N) {
        int nA = n0;
        int nB = (n0 + 1 < N) ? n0 + 1 : n0;
        int2 rA = rse[nA];
        int2 rB = rse[nB];
        int cA0 = rA.x, cA1 = rA.y;
        int cB0 = rB.x, cB1 = rB.y;
        bool hasA = cA0 < cA1, hasB = cB0 < cB1;
        h8 sA = P8[(size_t)nA * 16 + s];
        h8 sB = P8[(size_t)nB * 16 + s];
        float aA[8] = {}, aB[8] = {};
        // first 16-edge batches of A and B, dual-issued (8 loads/lane each)
        {
            h8 tA[8], tB[8];
            float wA[8], wB[8];
#pragma unroll
            for (int i = 0; i < 8; ++i) {
                int ei = cA0 + 2 * i + p;
                int ec = (ei < cA1) ? ei : (hasA ? cA1 - 1 : 0);
                tA[i] = P8[(size_t)(ed[ec].x & SRCMASK) * 16 + s];
                wA[i] = (ei < cA1) ? 1.f : 0.f;
            }
#pragma unroll
            for (int i = 0; i < 8; ++i) {
                int ei = cB0 + 2 * i + p;
                int ec = (ei < cB1) ? ei : (hasB ? cB1 - 1 : 0);
                tB[i] = P8[(size_t)(ed[ec].x & SRCMASK) * 16 + s];
                wB[i] = (ei < cB1) ? 1.f : 0.f;
            }
#pragma unroll
            for (int i = 0; i < 8; ++i)
#pragma unroll
                for (int f = 0; f < 8; ++f) aA[f] = fmaf(wA[i], (float)tA[i][f], aA[f]);
#pragma unroll
            for (int i = 0; i < 8; ++i)
#pragma unroll
                for (int f = 0; f < 8; ++f) aB[f] = fmaf(wB[i], (float)tB[i][f], aB[f]);
        }
        // tails (deg > 16)
        for (int eb = cA0 + 16; eb < cA1; eb += 16) {
            h8 t[8];
            float w[8];
#pragma unroll
            for (int i = 0; i < 8; ++i) {
                int ei = eb + 2 * i + p;
                int ec = (ei < cA1) ? ei : cA1 - 1;
                t[i] = P8[(size_t)(ed[ec].x & SRCMASK) * 16 + s];
                w[i] = (ei < cA1) ? 1.f : 0.f;
            }
#pragma unroll
            for (int i = 0; i < 8; ++i)
#pragma unroll
                for (int f = 0; f < 8; ++f) aA[f] = fmaf(w[i], (float)t[i][f], aA[f]);
        }
        for (int eb = cB0 + 16; eb < cB1; eb += 16) {
            h8 t[8];
            float w[8];
#pragma unroll
            for (int i = 0; i < 8; ++i) {
                int ei = eb + 2 * i + p;
                int ec = (ei < cB1) ? ei : cB1 - 1;
                t[i] = P8[(size_t)(ed[ec].x & SRCMASK) * 16 + s];
                w[i] = (ei < cB1) ? 1.f : 0.f;
            }
#pragma unroll
            for (int i = 0; i < 8; ++i)
#pragma unroll
                for (int f = 0; f < 8; ++f) aB[f] = fmaf(w[i], (float)t[i][f], aB[f]);
        }
        // cross-parity reduce, then self + bias + relu
        float dA = dinv[nA], dB = dinv[nB];
        int gA = batch[nA], gB = batch[nB];
        float4 bb0 = *(const float4*)&b2[s * 8];
        float4 bb1 = *(const float4*)&b2[s * 8 + 4];
        float bv[8] = {bb0.x, bb0.y, bb0.z, bb0.w, bb1.x, bb1.y, bb1.z, bb1.w};
        float zA[8], zB[8];
#pragma unroll
        for (int f = 0; f < 8; ++f) {
            float a = aA[f] + __shfl_xor(aA[f], 16);
            float b = aB[f] + __shfl_xor(aB[f], 16);
            zA[f] = fmaxf(fmaf(dA, (float)sA[f] + a, bv[f]), 0.f);
            zB[f] = fmaxf(fmaf(dB, (float)sB[f] + b, bv[f]), 0.f);
        }
        auto emit = [&](int g, const float* m) {
            if (p != 0) return;  // parities hold identical values post-reduce
            int slot = g - gfirst;
            if (slot < 4) {
#pragma unroll
                for (int f = 0; f < 8; ++f) {
                    int ff = (f + s) & 7;  // bank rotation
                    if (m[ff] > 0.f) atomicMax(&lpool[slot][s * 8 + ff], __float_as_int(m[ff]));
                }
            } else {
                float* pg = pool + (size_t)g * 128 + s * 8;
#pragma unroll
                for (int f = 0; f < 8; ++f)
                    if (m[f] > 0.f) atomicMax((int*)(pg + f), __float_as_int(m[f]));
            }
        };
        if (gA == gB) {
            float m[8];
#pragma unroll
            for (int f = 0; f < 8; ++f) m[f] = fmaxf(zA[f], zB[f]);
            emit(gA, m);
        } else {
            emit(gA, zA);
            emit(gB, zB);
        }
    }
    __syncthreads();
    {
        int f = tid & 127;
        for (int sl = tid >> 7; sl < 4; sl += 2) {
            int v = lpool[sl][f];
            if (v > 0) atomicMax((int*)&pool[(size_t)(gfirst + sl) * 128 + f], v);
        }
    }
}

// out[g][c] = blin[c] + sum_f pool[g][f] * Wlin[f][c]
__global__ __launch_bounds__(256) void k_final(const float* __restrict__ pool, const float* __restrict__ Wlin,
                                               const float* __restrict__ blin, float* __restrict__ out, int G) {
    int t = blockIdx.x * 256 + threadIdx.x;
    if (t >= G * 10) return;
    int g = t / 10, c = t % 10;
    float acc = blin[c];
    const float* pr = pool + (size_t)g * 128;
#pragma unroll 8
    for (int f = 0; f < 128; ++f) acc = fmaf(pr[f], Wlin[f * 10 + c], acc);
    out[t] = acc;
}

extern "C" void kernel_launch(void* const* d_in, const int* in_sizes, int n_in,
                              void* d_out, int out_size, void* d_ws, size_t ws_size,
                              hipStream_t stream) {
    const int* x = (const int*)d_in[0];
    const int* ei = (const int*)d_in[1];
    const int* batch = (const int*)d_in[2];
    const float* emb = (const float*)d_in[4];
    const float* W1 = (const float*)d_in[5];
    const float* b1 = (const float*)d_in[6];
    const float* W2 = (const float*)d_in[7];
    const float* b2 = (const float*)d_in[8];
    const float* Wlin = (const float*)d_in[9];
    const float* blin = (const float*)d_in[10];
    float* out = (float*)d_out;

    int N = in_sizes[0];
    int E = in_sizes[1] / 2;
    int VOCAB = in_sizes[4] / 64;
    int G = out_size / 10;
    const int* srcp = ei;
    const int* dstp = ei + E;

    char* p = (char*)d_ws;
    auto alloc = [&](size_t bytes) -> char* {
        char* r = p;
        p += (bytes + 255) & ~(size_t)255;
        return r;
    };
    int* deg = (int*)alloc((size_t)N * 4);
    int* exc = (int*)alloc((size_t)N * 4);
    int* cursor = (int*)alloc((size_t)N * 4);
    int2* rse = (int2*)alloc((size_t)N * 8);
    int* bsums = (int*)alloc(512 * 4);
    float* dinv = (float*)alloc((size_t)N * 4);
    int2* ed = (int2*)alloc((size_t)E * 8);
    _Float16* e16 = (_Float16*)alloc((size_t)VOCAB * 64 * 2);
    _Float16* W1T = (_Float16*)alloc(128 * 64 * 2);
    _Float16* W2T = (_Float16*)alloc(128 * 128 * 2);
    _Float16* P = (_Float16*)alloc((size_t)N * 128 * 2);
    float* pool = (float*)alloc((size_t)G * 128 * 4);

    int gE = (E + 255) / 256;
    int gN = (N + 255) / 256;  // 391 <= 512 (scan2 capacity)
    int nEmbF = VOCAB * 64;
    int nCast = (nEmbF / 4 + 255) / 256;

    int n4i = N / 4, p4i = G * 128 / 4;
    int zg = ((n4i > p4i ? n4i : p4i) + 255) / 256;
    k_zero<<<zg, 256, 0, stream>>>((int4*)deg, n4i, (int4*)pool, p4i);
    k_degprep<<<gE + nCast + 32 + 64, 256, 0, stream>>>(dstp, deg, E, emb, (__half2*)e16, W1, W1T,
                                                        W2, W2T, nEmbF, gE, nCast);
    k_scan1<<<gN, 256, 0, stream>>>(deg, exc, bsums, dinv, N);
    k_scan2<<<1, 512, 0, stream>>>(bsums, gN);
    k_scan3<<<gN, 256, 0, stream>>>(exc, cursor, bsums, rse, N, E);
    k_fill<<<gE, 256, 0, stream>>>(srcp, dstp, x, dinv, cursor, ed, E);
    k_mlp<<<(N + 15) / 16, 256, 0, stream>>>((const __half2*)e16, x, dinv, rse, ed, W1T, b1,
                                             W2T, P, N);
    k_agg2pool<<<(N + 15) / 16, 256, 0, stream>>>((const h8*)P, batch, dinv, rse, ed,
                                                  b2, pool, N, G);
    k_final<<<(G * 10 + 255) / 256, 256, 0, stream>>>(pool, Wlin, blin, out, G);
}

// Round 20
// 175.416 us; speedup vs baseline: 1.0417x; 1.0236x over previous
//
#include <hip/hip_runtime.h>
#include <hip/hip_bf16.h>
#include <hip/hip_fp16.h>

// GCN forward: emb-gather -> GCNConv(64->128) -> ReLU -> GCNConv(128->128) -> ReLU
//              -> global_max_pool -> Linear(128->10)
// N=100000, E=600000, VOCAB=5000, G=2000, C=10.
// Packed edge record (8B): ed = { x[src]<<17 | src , dinv[src] bits }.
// k_mlp / k_agg2pool use __launch_bounds__(256, 4): allow ~128 VGPRs so the full
// gather batch stays in flight (VGPR-40 build serialized loads on s_waitcnt).

typedef _Float16 h8 __attribute__((ext_vector_type(8)));
typedef float f32x4 __attribute__((ext_vector_type(4)));
#define SRCMASK 0x1FFFF

// Zero deg (n4i int4s) and pool (p4i int4s).
__global__ __launch_bounds__(256) void k_zero(int4* __restrict__ deg, int n4i,
                                              int4* __restrict__ pool, int p4i) {
    int t = blockIdx.x * 256 + threadIdx.x;
    int4 z = make_int4(0, 0, 0, 0);
    if (t < n4i) deg[t] = z;
    if (t < p4i) pool[t] = z;
}

// Fused: [0,gE) degree atomics; [gE,gE+nCast) e16 = fp16(emb); then W1T; then W2T.
__global__ __launch_bounds__(256) void k_degprep(const int* __restrict__ dst, int* __restrict__ deg, int E,
                                                 const float* __restrict__ emb, __half2* __restrict__ e16,
                                                 const float* __restrict__ W1, _Float16* __restrict__ W1T,
                                                 const float* __restrict__ W2, _Float16* __restrict__ W2T,
                                                 int nEmbF, int gE, int nCast) {
    int bid = blockIdx.x;
    if (bid < gE) {
        int e = bid * 256 + threadIdx.x;
        if (e < E) atomicAdd(&deg[dst[e]], 1);
    } else if (bid < gE + nCast) {
        int t = (bid - gE) * 256 + threadIdx.x;  // one thread = 4 floats
        if (t * 4 < nEmbF) {
            float4 v = *(const float4*)&emb[t * 4];
            e16[t * 2] = __floats2half2_rn(v.x, v.y);
            e16[t * 2 + 1] = __floats2half2_rn(v.z, v.w);
        }
    } else if (bid < gE + nCast + 32) {
        int t = (bid - gE - nCast) * 256 + threadIdx.x;  // 128*64
        int c = t >> 6, k = t & 63;
        W1T[c * 64 + k] = (_Float16)W1[k * 128 + c];
    } else {
        int t = (bid - gE - nCast - 32) * 256 + threadIdx.x;  // 128*128
        if (t < 128 * 128) {
            int c = t >> 7, k = t & 127;
            W2T[c * 128 + k] = (_Float16)W2[k * 128 + c];
        }
    }
}

// scan1 + dinv fused: exc = block-local exclusive scan of deg
__global__ __launch_bounds__(256) void k_scan1(const int* __restrict__ deg, int* __restrict__ exc,
                                               int* __restrict__ bsums, float* __restrict__ dinv, int N) {
    __shared__ int s[256];
    int i = blockIdx.x * 256 + threadIdx.x;
    int v = (i < N) ? deg[i] : 0;
    if (i < N) dinv[i] = rsqrtf((float)(v + 1));  // +1 self-loop
    s[threadIdx.x] = v;
    __syncthreads();
    for (int off = 1; off < 256; off <<= 1) {
        int t = (threadIdx.x >= (unsigned)off) ? s[threadIdx.x - off] : 0;
        __syncthreads();
        s[threadIdx.x] += t;
        __syncthreads();
    }
    if (i < N) exc[i] = s[threadIdx.x] - v;
    if (threadIdx.x == 255) bsums[blockIdx.x] = s[255];
}

__global__ __launch_bounds__(512) void k_scan2(int* __restrict__ bsums, int nb) {
    __shared__ int s[512];
    int i = threadIdx.x;
    int v = (i < nb) ? bsums[i] : 0;
    s[i] = v;
    __syncthreads();
    for (int off = 1; off < 512; off <<= 1) {
        int t = (i >= off) ? s[i - off] : 0;
        __syncthreads();
        s[i] += t;
        __syncthreads();
    }
    if (i < nb) bsums[i] = s[i] - v;
}

// scan3: cursor[i] = global rowstart; rse[i] = {start, end}
__global__ __launch_bounds__(256) void k_scan3(const int* __restrict__ exc, int* __restrict__ cursor,
                                               const int* __restrict__ bsums, int2* __restrict__ rse,
                                               int N, int E) {
    int i = blockIdx.x * 256 + threadIdx.x;
    if (i < N) {
        int r = exc[i] + bsums[blockIdx.x];
        int rn = (i + 1 < N) ? exc[i + 1] + bsums[(i + 1) >> 8] : E;
        cursor[i] = r;
        rse[i] = make_int2(r, rn);
    }
}

// CSR fill: ed[pos] = { x[src]<<17 | src , dinv[src] bits } — ONE 8B scattered store.
__global__ __launch_bounds__(256) void k_fill(const int* __restrict__ src, const int* __restrict__ dst,
                                              const int* __restrict__ x, const float* __restrict__ dinv,
                                              int* __restrict__ cursor, int2* __restrict__ ed, int E) {
    int e = blockIdx.x * 256 + threadIdx.x;
    if (e < E) {
        int d = dst[e];
        int s = src[e];
        int pos = atomicAdd(&cursor[d], 1);
        ed[pos] = make_int2((x[s] << 17) | s, __float_as_int(dinv[s]));
    }
}

// Fused node pipeline: 256 threads, block = 16 nodes. launch_bounds(256,4): keep
// the whole gather batch in flight (loads-first, consume-after).
__global__ __launch_bounds__(256, 4) void k_mlp(const __half2* __restrict__ e16, const int* __restrict__ x,
                                                const float* __restrict__ dinv, const int2* __restrict__ rse,
                                                const int2* __restrict__ ed, const _Float16* __restrict__ W1T,
                                                const float* __restrict__ b1, const _Float16* __restrict__ W2T,
                                                _Float16* __restrict__ P, int N) {
    __shared__ _Float16 Xs[16][72];    // 64-dim rows, stride 144B
    __shared__ _Float16 Hs[16][136];   // 128-dim rows, stride 272B
    int tid = threadIdx.x;
    int blk0 = blockIdx.x * 16;
    // ---- Phase 1 ----
    {
        int lane = tid & 31;
        int hw = tid >> 5;   // 0..7
        int p = lane >> 3;   // 0..3 quad
        int f16 = lane & 7;  // h8 slot (8 fp16 feats)
        const h8* e8 = (const h8*)e16;
        int nlA = hw * 2, nlB = nlA + 1;
        int gA = blk0 + nlA; if (gA >= N) gA = N - 1;
        int gB = blk0 + nlB; if (gB >= N) gB = N - 1;
        int2 rA = rse[gA];
        int2 rB = rse[gB];
        int cA0 = rA.x, cA1 = rA.y;
        int cB0 = rB.x, cB1 = rB.y;
        int baseA = (cA0 < cA1) ? cA1 - 1 : 0;
        int baseB = (cB0 < cB1) ? cB1 - 1 : 0;
        float dA = dinv[gA], dB = dinv[gB];
        h8 selfA = e8[(size_t)x[gA] * 8 + f16];
        h8 selfB = e8[(size_t)x[gB] * 8 + f16];
        float accA[8] = {}, accB[8] = {};
        // first batches of A and B: ALL loads issued, then all FMAs (needs ~5 h8 regs live)
        {
            int eA0 = cA0 + p, eA1 = cA0 + 4 + p;
            int eB0 = cB0 + p, eB1 = cB0 + 4 + p;
            int2 rA0 = ed[(eA0 < cA1) ? eA0 : baseA];
            int2 rA1 = ed[(eA1 < cA1) ? eA1 : baseA];
            int2 rB0 = ed[(eB0 < cB1) ? eB0 : baseB];
            int2 rB1 = ed[(eB1 < cB1) ? eB1 : baseB];
            h8 t[4];
            t[0] = e8[(size_t)((unsigned)rA0.x >> 17) * 8 + f16];
            t[1] = e8[(size_t)((unsigned)rA1.x >> 17) * 8 + f16];
            t[2] = e8[(size_t)((unsigned)rB0.x >> 17) * 8 + f16];
            t[3] = e8[(size_t)((unsigned)rB1.x >> 17) * 8 + f16];
            float wA0 = (eA0 < cA1) ? __int_as_float(rA0.y) : 0.f;
            float wA1 = (eA1 < cA1) ? __int_as_float(rA1.y) : 0.f;
            float wB0 = (eB0 < cB1) ? __int_as_float(rB0.y) : 0.f;
            float wB1 = (eB1 < cB1) ? __int_as_float(rB1.y) : 0.f;
#pragma unroll
            for (int f = 0; f < 8; ++f) {
                accA[f] = fmaf(wA1, (float)t[1][f], fmaf(wA0, (float)t[0][f], accA[f]));
                accB[f] = fmaf(wB1, (float)t[3][f], fmaf(wB0, (float)t[2][f], accB[f]));
            }
        }
        // tails (deg > 8)
        for (int eb = cA0 + 8; eb < cA1; eb += 8) {
            int e0 = eb + p, e1i = eb + 4 + p;
            int2 r0 = ed[(e0 < cA1) ? e0 : cA1 - 1];
            int2 r1 = ed[(e1i < cA1) ? e1i : cA1 - 1];
            h8 t0 = e8[(size_t)((unsigned)r0.x >> 17) * 8 + f16];
            h8 t1 = e8[(size_t)((unsigned)r1.x >> 17) * 8 + f16];
            float w0 = (e0 < cA1) ? __int_as_float(r0.y) : 0.f;
            float w1 = (e1i < cA1) ? __int_as_float(r1.y) : 0.f;
#pragma unroll
            for (int f = 0; f < 8; ++f)
                accA[f] = fmaf(w1, (float)t1[f], fmaf(w0, (float)t0[f], accA[f]));
        }
        for (int eb = cB0 + 8; eb < cB1; eb += 8) {
            int e0 = eb + p, e1i = eb + 4 + p;
            int2 r0 = ed[(e0 < cB1) ? e0 : cB1 - 1];
            int2 r1 = ed[(e1i < cB1) ? e1i : cB1 - 1];
            h8 t0 = e8[(size_t)((unsigned)r0.x >> 17) * 8 + f16];
            h8 t1 = e8[(size_t)((unsigned)r1.x >> 17) * 8 + f16];
            float w0 = (e0 < cB1) ? __int_as_float(r0.y) : 0.f;
            float w1 = (e1i < cB1) ? __int_as_float(r1.y) : 0.f;
#pragma unroll
            for (int f = 0; f < 8; ++f)
                accB[f] = fmaf(w1, (float)t1[f], fmaf(w0, (float)t0[f], accB[f]));
        }
        // cross-quad reduce + self + scale, p==0 writes
        h8 yA, yB;
#pragma unroll
        for (int f = 0; f < 8; ++f) {
            float a = accA[f];
            a += __shfl_xor(a, 8);
            a += __shfl_xor(a, 16);
            float b = accB[f];
            b += __shfl_xor(b, 8);
            b += __shfl_xor(b, 16);
            yA[f] = (_Float16)(dA * fmaf(dA, (float)selfA[f], a));
            yB[f] = (_Float16)(dB * fmaf(dB, (float)selfB[f], b));
        }
        if (p == 0) {
            *(h8*)&Xs[nlA][f16 * 8] = yA;
            *(h8*)&Xs[nlB][f16 * 8] = yB;
        }
    }
    __syncthreads();
    int l = tid & 63, wid = tid >> 6;    // 4 waves
    int r = l & 15, kg = l >> 4;
    int ch = wid;                        // col quarter: 32 cols
    // ---- Phase 2: Hs = relu(Xs @ W1 + b1), wave = 16 rows x 32 cols ----
    {
        f32x4 acc[2];
#pragma unroll
        for (int ct = 0; ct < 2; ++ct) acc[ct] = (f32x4){0.f, 0.f, 0.f, 0.f};
#pragma unroll
        for (int kc = 0; kc < 2; ++kc) {
            h8 a = *(const h8*)&Xs[r][kc * 32 + kg * 8];
#pragma unroll
            for (int ct = 0; ct < 2; ++ct) {
                h8 b = *(const h8*)(W1T + (size_t)(ch * 32 + ct * 16 + r) * 64 + kc * 32 + kg * 8);
                acc[ct] = __builtin_amdgcn_mfma_f32_16x16x32_f16(a, b, acc[ct], 0, 0, 0);
            }
        }
#pragma unroll
        for (int ct = 0; ct < 2; ++ct) {
            float bias = b1[ch * 32 + ct * 16 + r];
#pragma unroll
            for (int i = 0; i < 4; ++i)
                Hs[4 * kg + i][ch * 32 + ct * 16 + r] = (_Float16)fmaxf(acc[ct][i] + bias, 0.f);
        }
    }
    __syncthreads();
    // ---- Phase 3: P = dinv * (Hs @ W2), wave = 16 rows x 32 cols ----
    {
        f32x4 acc[2];
#pragma unroll
        for (int ct = 0; ct < 2; ++ct) acc[ct] = (f32x4){0.f, 0.f, 0.f, 0.f};
#pragma unroll
        for (int kc = 0; kc < 4; ++kc) {
            h8 a = *(const h8*)&Hs[r][kc * 32 + kg * 8];
#pragma unroll
            for (int ct = 0; ct < 2; ++ct) {
                h8 b = *(const h8*)(W2T + (size_t)(ch * 32 + ct * 16 + r) * 128 + kc * 32 + kg * 8);
                acc[ct] = __builtin_amdgcn_mfma_f32_16x16x32_f16(a, b, acc[ct], 0, 0, 0);
            }
        }
        float dv[4];
#pragma unroll
        for (int i = 0; i < 4; ++i) {
            int gr = blk0 + 4 * kg + i;
            dv[i] = (gr < N) ? dinv[gr] : 0.f;
        }
#pragma unroll
        for (int ct = 0; ct < 2; ++ct) {
#pragma unroll
            for (int i = 0; i < 4; ++i) {
                int gr = blk0 + 4 * kg + i;
                if (gr < N)
                    P[(size_t)gr * 128 + ch * 32 + ct * 16 + r] = (_Float16)(acc[ct][i] * dv[i]);
            }
        }
    }
}

// Layer-2 + global_max_pool. launch_bounds(256,4): full 8-load batch in flight.
__global__ __launch_bounds__(256, 4) void k_agg2pool(const h8* __restrict__ P8, const int* __restrict__ batch,
                                                     const float* __restrict__ dinv, const int2* __restrict__ rse,
                                                     const int2* __restrict__ ed, const float* __restrict__ b2,
                                                     float* __restrict__ pool, int N, int G) {
    __shared__ int lpool[4][128];
    int tid = threadIdx.x;
    lpool[tid >> 7][tid & 127] = 0;
    lpool[(tid >> 7) + 2][tid & 127] = 0;
    __syncthreads();
    int lane = tid & 31;
    int p = lane >> 4;   // parity (edge subset)
    int s = lane & 15;   // h8 slot: feats s*8..s*8+7
    int blk_n0 = blockIdx.x * 16;
    int gfirst = batch[(blk_n0 < N) ? blk_n0 : (N - 1)];
    int n0 = blk_n0 + (tid >> 5) * 2;
    if (n0 < N) {
        int nA = n0;
        int nB = (n0 + 1 < N) ? n0 + 1 : n0;
        int2 rA = rse[nA];
        int2 rB = rse[nB];
        int cA0 = rA.x, cA1 = rA.y;
        int cB0 = rB.x, cB1 = rB.y;
        bool hasA = cA0 < cA1, hasB = cB0 < cB1;
        h8 sA = P8[(size_t)nA * 16 + s];
        h8 sB = P8[(size_t)nB * 16 + s];
        float aA[8] = {}, aB[8] = {};
        // first 16-edge batches of A and B, dual-issued (8 loads/lane each)
        {
            h8 tA[8], tB[8];
            float wA[8], wB[8];
#pragma unroll
            for (int i = 0; i < 8; ++i) {
                int ei = cA0 + 2 * i + p;
                int ec = (ei < cA1) ? ei : (hasA ? cA1 - 1 : 0);
                tA[i] = P8[(size_t)(ed[ec].x & SRCMASK) * 16 + s];
                wA[i] = (ei < cA1) ? 1.f : 0.f;
            }
#pragma unroll
            for (int i = 0; i < 8; ++i) {
                int ei = cB0 + 2 * i + p;
                int ec = (ei < cB1) ? ei : (hasB ? cB1 - 1 : 0);
                tB[i] = P8[(size_t)(ed[ec].x & SRCMASK) * 16 + s];
                wB[i] = (ei < cB1) ? 1.f : 0.f;
            }
#pragma unroll
            for (int i = 0; i < 8; ++i)
#pragma unroll
                for (int f = 0; f < 8; ++f) aA[f] = fmaf(wA[i], (float)tA[i][f], aA[f]);
#pragma unroll
            for (int i = 0; i < 8; ++i)
#pragma unroll
                for (int f = 0; f < 8; ++f) aB[f] = fmaf(wB[i], (float)tB[i][f], aB[f]);
        }
        // tails (deg > 16)
        for (int eb = cA0 + 16; eb < cA1; eb += 16) {
            h8 t[8];
            float w[8];
#pragma unroll
            for (int i = 0; i < 8; ++i) {
                int ei = eb + 2 * i + p;
                int ec = (ei < cA1) ? ei : cA1 - 1;
                t[i] = P8[(size_t)(ed[ec].x & SRCMASK) * 16 + s];
                w[i] = (ei < cA1) ? 1.f : 0.f;
            }
#pragma unroll
            for (int i = 0; i < 8; ++i)
#pragma unroll
                for (int f = 0; f < 8; ++f) aA[f] = fmaf(w[i], (float)t[i][f], aA[f]);
        }
        for (int eb = cB0 + 16; eb < cB1; eb += 16) {
            h8 t[8];
            float w[8];
#pragma unroll
            for (int i = 0; i < 8; ++i) {
                int ei = eb + 2 * i + p;
                int ec = (ei < cB1) ? ei : cB1 - 1;
                t[i] = P8[(size_t)(ed[ec].x & SRCMASK) * 16 + s];
                w[i] = (ei < cB1) ? 1.f : 0.f;
            }
#pragma unroll
            for (int i = 0; i < 8; ++i)
#pragma unroll
                for (int f = 0; f < 8; ++f) aB[f] = fmaf(w[i], (float)t[i][f], aB[f]);
        }
        // cross-parity reduce, then self + bias + relu
        float dA = dinv[nA], dB = dinv[nB];
        int gA = batch[nA], gB = batch[nB];
        float4 bb0 = *(const float4*)&b2[s * 8];
        float4 bb1 = *(const float4*)&b2[s * 8 + 4];
        float bv[8] = {bb0.x, bb0.y, bb0.z, bb0.w, bb1.x, bb1.y, bb1.z, bb1.w};
        float zA[8], zB[8];
#pragma unroll
        for (int f = 0; f < 8; ++f) {
            float a = aA[f] + __shfl_xor(aA[f], 16);
            float b = aB[f] + __shfl_xor(aB[f], 16);
            zA[f] = fmaxf(fmaf(dA, (float)sA[f] + a, bv[f]), 0.f);
            zB[f] = fmaxf(fmaf(dB, (float)sB[f] + b, bv[f]), 0.f);
        }
        auto emit = [&](int g, const float* m) {
            if (p != 0) return;  // parities hold identical values post-reduce
            int slot = g - gfirst;
            if (slot < 4) {
#pragma unroll
                for (int f = 0; f < 8; ++f) {
                    int ff = (f + s) & 7;  // bank rotation
                    if (m[ff] > 0.f) atomicMax(&lpool[slot][s * 8 + ff], __float_as_int(m[ff]));
                }
            } else {
                float* pg = pool + (size_t)g * 128 + s * 8;
#pragma unroll
                for (int f = 0; f < 8; ++f)
                    if (m[f] > 0.f) atomicMax((int*)(pg + f), __float_as_int(m[f]));
            }
        };
        if (gA == gB) {
            float m[8];
#pragma unroll
            for (int f = 0; f < 8; ++f) m[f] = fmaxf(zA[f], zB[f]);
            emit(gA, m);
        } else {
            emit(gA, zA);
            emit(gB, zB);
        }
    }
    __syncthreads();
    {
        int f = tid & 127;
        for (int sl = tid >> 7; sl < 4; sl += 2) {
            int v = lpool[sl][f];
            if (v > 0) atomicMax((int*)&pool[(size_t)(gfirst + sl) * 128 + f], v);
        }
    }
}

// out[g][c] = blin[c] + sum_f pool[g][f] * Wlin[f][c]
__global__ __launch_bounds__(256) void k_final(const float* __restrict__ pool, const float* __restrict__ Wlin,
                                               const float* __restrict__ blin, float* __restrict__ out, int G) {
    int t = blockIdx.x * 256 + threadIdx.x;
    if (t >= G * 10) return;
    int g = t / 10, c = t % 10;
    float acc = blin[c];
    const float* pr = pool + (size_t)g * 128;
#pragma unroll 8
    for (int f = 0; f < 128; ++f) acc = fmaf(pr[f], Wlin[f * 10 + c], acc);
    out[t] = acc;
}

extern "C" void kernel_launch(void* const* d_in, const int* in_sizes, int n_in,
                              void* d_out, int out_size, void* d_ws, size_t ws_size,
                              hipStream_t stream) {
    const int* x = (const int*)d_in[0];
    const int* ei = (const int*)d_in[1];
    const int* batch = (const int*)d_in[2];
    const float* emb = (const float*)d_in[4];
    const float* W1 = (const float*)d_in[5];
    const float* b1 = (const float*)d_in[6];
    const float* W2 = (const float*)d_in[7];
    const float* b2 = (const float*)d_in[8];
    const float* Wlin = (const float*)d_in[9];
    const float* blin = (const float*)d_in[10];
    float* out = (float*)d_out;

    int N = in_sizes[0];
    int E = in_sizes[1] / 2;
    int VOCAB = in_sizes[4] / 64;
    int G = out_size / 10;
    const int* srcp = ei;
    const int* dstp = ei + E;

    char* p = (char*)d_ws;
    auto alloc = [&](size_t bytes) -> char* {
        char* r = p;
        p += (bytes + 255) & ~(size_t)255;
        return r;
    };
    int* deg = (int*)alloc((size_t)N * 4);
    int* exc = (int*)alloc((size_t)N * 4);
    int* cursor = (int*)alloc((size_t)N * 4);
    int2* rse = (int2*)alloc((size_t)N * 8);
    int* bsums = (int*)alloc(512 * 4);
    float* dinv = (float*)alloc((size_t)N * 4);
    int2* ed = (int2*)alloc((size_t)E * 8);
    _Float16* e16 = (_Float16*)alloc((size_t)VOCAB * 64 * 2);
    _Float16* W1T = (_Float16*)alloc(128 * 64 * 2);
    _Float16* W2T = (_Float16*)alloc(128 * 128 * 2);
    _Float16* P = (_Float16*)alloc((size_t)N * 128 * 2);
    float* pool = (float*)alloc((size_t)G * 128 * 4);

    int gE = (E + 255) / 256;
    int gN = (N + 255) / 256;  // 391 <= 512 (scan2 capacity)
    int nEmbF = VOCAB * 64;
    int nCast = (nEmbF / 4 + 255) / 256;

    int n4i = N / 4, p4i = G * 128 / 4;
    int zg = ((n4i > p4i ? n4i : p4i) + 255) / 256;
    k_zero<<<zg, 256, 0, stream>>>((int4*)deg, n4i, (int4*)pool, p4i);
    k_degprep<<<gE + nCast + 32 + 64, 256, 0, stream>>>(dstp, deg, E, emb, (__half2*)e16, W1, W1T,
                                                        W2, W2T, nEmbF, gE, nCast);
    k_scan1<<<gN, 256, 0, stream>>>(deg, exc, bsums, dinv, N);
    k_scan2<<<1, 512, 0, stream>>>(bsums, gN);
    k_scan3<<<gN, 256, 0, stream>>>(exc, cursor, bsums, rse, N, E);
    k_fill<<<gE, 256, 0, stream>>>(srcp, dstp, x, dinv, cursor, ed, E);
    k_mlp<<<(N + 15) / 16, 256, 0, stream>>>((const __half2*)e16, x, dinv, rse, ed, W1T, b1,
                                             W2T, P, N);
    k_agg2pool<<<(N + 15) / 16, 256, 0, stream>>>((const h8*)P, batch, dinv, rse, ed,
                                                  b2, pool, N, G);
    k_final<<<(G * 10 + 255) / 256, 256, 0, stream>>>(pool, Wlin, blin, out, G);
}

// Round 21
// 174.419 us; speedup vs baseline: 1.0476x; 1.0057x over previous
//
#include <hip/hip_runtime.h>
#include <hip/hip_bf16.h>
#include <hip/hip_fp16.h>

// GCN forward: emb-gather -> GCNConv(64->128) -> ReLU -> GCNConv(128->128) -> ReLU
//              -> global_max_pool -> Linear(128->10)
// N=100000, E=600000, VOCAB=5000, G=2000, C=10.
// Packed edge record (8B): ed = { x[src]<<17 | src , dinv[src] bits }.
// 8 launches: zero(deg), degprep, scan1(+pool zero), scan23, fill, mlp, agg2pool, final.

typedef _Float16 h8 __attribute__((ext_vector_type(8)));
typedef float f32x4 __attribute__((ext_vector_type(4)));
#define SRCMASK 0x1FFFF

// Zero deg (n4i int4s).
__global__ __launch_bounds__(256) void k_zero(int4* __restrict__ deg, int n4i) {
    int t = blockIdx.x * 256 + threadIdx.x;
    if (t < n4i) deg[t] = make_int4(0, 0, 0, 0);
}

// Fused: [0,gE) degree atomics; [gE,gE+nCast) e16 = fp16(emb); then W1T; then W2T.
__global__ __launch_bounds__(256) void k_degprep(const int* __restrict__ dst, int* __restrict__ deg, int E,
                                                 const float* __restrict__ emb, __half2* __restrict__ e16,
                                                 const float* __restrict__ W1, _Float16* __restrict__ W1T,
                                                 const float* __restrict__ W2, _Float16* __restrict__ W2T,
                                                 int nEmbF, int gE, int nCast) {
    int bid = blockIdx.x;
    if (bid < gE) {
        int e = bid * 256 + threadIdx.x;
        if (e < E) atomicAdd(&deg[dst[e]], 1);
    } else if (bid < gE + nCast) {
        int t = (bid - gE) * 256 + threadIdx.x;  // one thread = 4 floats
        if (t * 4 < nEmbF) {
            float4 v = *(const float4*)&emb[t * 4];
            e16[t * 2] = __floats2half2_rn(v.x, v.y);
            e16[t * 2 + 1] = __floats2half2_rn(v.z, v.w);
        }
    } else if (bid < gE + nCast + 32) {
        int t = (bid - gE - nCast) * 256 + threadIdx.x;  // 128*64
        int c = t >> 6, k = t & 63;
        W1T[c * 64 + k] = (_Float16)W1[k * 128 + c];
    } else {
        int t = (bid - gE - nCast - 32) * 256 + threadIdx.x;  // 128*128
        if (t < 128 * 128) {
            int c = t >> 7, k = t & 127;
            W2T[c * 128 + k] = (_Float16)W2[k * 128 + c];
        }
    }
}

// scan1 + dinv + pool-zero fused: exc = block-local exclusive scan of deg
__global__ __launch_bounds__(256) void k_scan1(const int* __restrict__ deg, int* __restrict__ exc,
                                               int* __restrict__ bsums, float* __restrict__ dinv,
                                               int4* __restrict__ pool4, int p4i, int N) {
    __shared__ int s[256];
    int i = blockIdx.x * 256 + threadIdx.x;
    if (i < p4i) pool4[i] = make_int4(0, 0, 0, 0);
    int v = (i < N) ? deg[i] : 0;
    if (i < N) dinv[i] = rsqrtf((float)(v + 1));  // +1 self-loop
    s[threadIdx.x] = v;
    __syncthreads();
    for (int off = 1; off < 256; off <<= 1) {
        int t = (threadIdx.x >= (unsigned)off) ? s[threadIdx.x - off] : 0;
        __syncthreads();
        s[threadIdx.x] += t;
        __syncthreads();
    }
    if (i < N) exc[i] = s[threadIdx.x] - v;
    if (threadIdx.x == 255) bsums[blockIdx.x] = s[255];
}

// scan2+scan3 fused: every block re-scans bsums (nb<=512) in LDS, then emits
// cursor[i] (global rowstart) and rse[i] = {start,end}.
__global__ __launch_bounds__(512) void k_scan23(const int* __restrict__ exc, const int* __restrict__ bsums,
                                                int* __restrict__ cursor, int2* __restrict__ rse,
                                                int N, int E, int nb) {
    __shared__ int s[512];
    int t = threadIdx.x;
    int v = (t < nb) ? bsums[t] : 0;
    s[t] = v;
    __syncthreads();
    for (int off = 1; off < 512; off <<= 1) {
        int tv = (t >= off) ? s[t - off] : 0;
        __syncthreads();
        s[t] += tv;
        __syncthreads();
    }
    s[t] -= v;  // exclusive
    __syncthreads();
    int i = blockIdx.x * 512 + t;
    if (i < N) {
        int r = exc[i] + s[i >> 8];
        int rn = (i + 1 < N) ? exc[i + 1] + s[(i + 1) >> 8] : E;
        cursor[i] = r;
        rse[i] = make_int2(r, rn);
    }
}

// CSR fill: ed[pos] = { x[src]<<17 | src , dinv[src] bits } — ONE 8B scattered store.
__global__ __launch_bounds__(256) void k_fill(const int* __restrict__ src, const int* __restrict__ dst,
                                              const int* __restrict__ x, const float* __restrict__ dinv,
                                              int* __restrict__ cursor, int2* __restrict__ ed, int E) {
    int e = blockIdx.x * 256 + threadIdx.x;
    if (e < E) {
        int d = dst[e];
        int s = src[e];
        int pos = atomicAdd(&cursor[d], 1);
        ed[pos] = make_int2((x[s] << 17) | s, __float_as_int(dinv[s]));
    }
}

// Fused node pipeline: 256 threads, block = 16 nodes.
__global__ __launch_bounds__(256, 4) void k_mlp(const __half2* __restrict__ e16, const int* __restrict__ x,
                                                const float* __restrict__ dinv, const int2* __restrict__ rse,
                                                const int2* __restrict__ ed, const _Float16* __restrict__ W1T,
                                                const float* __restrict__ b1, const _Float16* __restrict__ W2T,
                                                _Float16* __restrict__ P, int N) {
    __shared__ _Float16 Xs[16][72];    // 64-dim rows, stride 144B
    __shared__ _Float16 Hs[16][136];   // 128-dim rows, stride 272B
    int tid = threadIdx.x;
    int blk0 = blockIdx.x * 16;
    // ---- Phase 1 ----
    {
        int lane = tid & 31;
        int hw = tid >> 5;   // 0..7
        int p = lane >> 3;   // 0..3 quad
        int f16 = lane & 7;  // h8 slot (8 fp16 feats)
        const h8* e8 = (const h8*)e16;
        int nlA = hw * 2, nlB = nlA + 1;
        int gA = blk0 + nlA; if (gA >= N) gA = N - 1;
        int gB = blk0 + nlB; if (gB >= N) gB = N - 1;
        int2 rA = rse[gA];
        int2 rB = rse[gB];
        int cA0 = rA.x, cA1 = rA.y;
        int cB0 = rB.x, cB1 = rB.y;
        int baseA = (cA0 < cA1) ? cA1 - 1 : 0;
        int baseB = (cB0 < cB1) ? cB1 - 1 : 0;
        float dA = dinv[gA], dB = dinv[gB];
        h8 selfA = e8[(size_t)x[gA] * 8 + f16];
        h8 selfB = e8[(size_t)x[gB] * 8 + f16];
        float accA[8] = {}, accB[8] = {};
        {
            int eA0 = cA0 + p, eA1 = cA0 + 4 + p;
            int eB0 = cB0 + p, eB1 = cB0 + 4 + p;
            int2 rA0 = ed[(eA0 < cA1) ? eA0 : baseA];
            int2 rA1 = ed[(eA1 < cA1) ? eA1 : baseA];
            int2 rB0 = ed[(eB0 < cB1) ? eB0 : baseB];
            int2 rB1 = ed[(eB1 < cB1) ? eB1 : baseB];
            h8 t[4];
            t[0] = e8[(size_t)((unsigned)rA0.x >> 17) * 8 + f16];
            t[1] = e8[(size_t)((unsigned)rA1.x >> 17) * 8 + f16];
            t[2] = e8[(size_t)((unsigned)rB0.x >> 17) * 8 + f16];
            t[3] = e8[(size_t)((unsigned)rB1.x >> 17) * 8 + f16];
            float wA0 = (eA0 < cA1) ? __int_as_float(rA0.y) : 0.f;
            float wA1 = (eA1 < cA1) ? __int_as_float(rA1.y) : 0.f;
            float wB0 = (eB0 < cB1) ? __int_as_float(rB0.y) : 0.f;
            float wB1 = (eB1 < cB1) ? __int_as_float(rB1.y) : 0.f;
#pragma unroll
            for (int f = 0; f < 8; ++f) {
                accA[f] = fmaf(wA1, (float)t[1][f], fmaf(wA0, (float)t[0][f], accA[f]));
                accB[f] = fmaf(wB1, (float)t[3][f], fmaf(wB0, (float)t[2][f], accB[f]));
            }
        }
        for (int eb = cA0 + 8; eb < cA1; eb += 8) {
            int e0 = eb + p, e1i = eb + 4 + p;
            int2 r0 = ed[(e0 < cA1) ? e0 : cA1 - 1];
            int2 r1 = ed[(e1i < cA1) ? e1i : cA1 - 1];
            h8 t0 = e8[(size_t)((unsigned)r0.x >> 17) * 8 + f16];
            h8 t1 = e8[(size_t)((unsigned)r1.x >> 17) * 8 + f16];
            float w0 = (e0 < cA1) ? __int_as_float(r0.y) : 0.f;
            float w1 = (e1i < cA1) ? __int_as_float(r1.y) : 0.f;
#pragma unroll
            for (int f = 0; f < 8; ++f)
                accA[f] = fmaf(w1, (float)t1[f], fmaf(w0, (float)t0[f], accA[f]));
        }
        for (int eb = cB0 + 8; eb < cB1; eb += 8) {
            int e0 = eb + p, e1i = eb + 4 + p;
            int2 r0 = ed[(e0 < cB1) ? e0 : cB1 - 1];
            int2 r1 = ed[(e1i < cB1) ? e1i : cB1 - 1];
            h8 t0 = e8[(size_t)((unsigned)r0.x >> 17) * 8 + f16];
            h8 t1 = e8[(size_t)((unsigned)r1.x >> 17) * 8 + f16];
            float w0 = (e0 < cB1) ? __int_as_float(r0.y) : 0.f;
            float w1 = (e1i < cB1) ? __int_as_float(r1.y) : 0.f;
#pragma unroll
            for (int f = 0; f < 8; ++f)
                accB[f] = fmaf(w1, (float)t1[f], fmaf(w0, (float)t0[f], accB[f]));
        }
        h8 yA, yB;
#pragma unroll
        for (int f = 0; f < 8; ++f) {
            float a = accA[f];
            a += __shfl_xor(a, 8);
            a += __shfl_xor(a, 16);
            float b = accB[f];
            b += __shfl_xor(b, 8);
            b += __shfl_xor(b, 16);
            yA[f] = (_Float16)(dA * fmaf(dA, (float)selfA[f], a));
            yB[f] = (_Float16)(dB * fmaf(dB, (float)selfB[f], b));
        }
        if (p == 0) {
            *(h8*)&Xs[nlA][f16 * 8] = yA;
            *(h8*)&Xs[nlB][f16 * 8] = yB;
        }
    }
    __syncthreads();
    int l = tid & 63, wid = tid >> 6;    // 4 waves
    int r = l & 15, kg = l >> 4;
    int ch = wid;                        // col quarter: 32 cols
    // ---- Phase 2: Hs = relu(Xs @ W1 + b1) ----
    {
        f32x4 acc[2];
#pragma unroll
        for (int ct = 0; ct < 2; ++ct) acc[ct] = (f32x4){0.f, 0.f, 0.f, 0.f};
#pragma unroll
        for (int kc = 0; kc < 2; ++kc) {
            h8 a = *(const h8*)&Xs[r][kc * 32 + kg * 8];
#pragma unroll
            for (int ct = 0; ct < 2; ++ct) {
                h8 b = *(const h8*)(W1T + (size_t)(ch * 32 + ct * 16 + r) * 64 + kc * 32 + kg * 8);
                acc[ct] = __builtin_amdgcn_mfma_f32_16x16x32_f16(a, b, acc[ct], 0, 0, 0);
            }
        }
#pragma unroll
        for (int ct = 0; ct < 2; ++ct) {
            float bias = b1[ch * 32 + ct * 16 + r];
#pragma unroll
            for (int i = 0; i < 4; ++i)
                Hs[4 * kg + i][ch * 32 + ct * 16 + r] = (_Float16)fmaxf(acc[ct][i] + bias, 0.f);
        }
    }
    __syncthreads();
    // ---- Phase 3: P = dinv * (Hs @ W2) ----
    {
        f32x4 acc[2];
#pragma unroll
        for (int ct = 0; ct < 2; ++ct) acc[ct] = (f32x4){0.f, 0.f, 0.f, 0.f};
#pragma unroll
        for (int kc = 0; kc < 4; ++kc) {
            h8 a = *(const h8*)&Hs[r][kc * 32 + kg * 8];
#pragma unroll
            for (int ct = 0; ct < 2; ++ct) {
                h8 b = *(const h8*)(W2T + (size_t)(ch * 32 + ct * 16 + r) * 128 + kc * 32 + kg * 8);
                acc[ct] = __builtin_amdgcn_mfma_f32_16x16x32_f16(a, b, acc[ct], 0, 0, 0);
            }
        }
        float dv[4];
#pragma unroll
        for (int i = 0; i < 4; ++i) {
            int gr = blk0 + 4 * kg + i;
            dv[i] = (gr < N) ? dinv[gr] : 0.f;
        }
#pragma unroll
        for (int ct = 0; ct < 2; ++ct) {
#pragma unroll
            for (int i = 0; i < 4; ++i) {
                int gr = blk0 + 4 * kg + i;
                if (gr < N)
                    P[(size_t)gr * 128 + ch * 32 + ct * 16 + r] = (_Float16)(acc[ct][i] * dv[i]);
            }
        }
    }
}

// Layer-2 + global_max_pool. 16B/lane parity gather + shfl_xor(16) reduce + LDS pool.
__global__ __launch_bounds__(256, 4) void k_agg2pool(const h8* __restrict__ P8, const int* __restrict__ batch,
                                                     const float* __restrict__ dinv, const int2* __restrict__ rse,
                                                     const int2* __restrict__ ed, const float* __restrict__ b2,
                                                     float* __restrict__ pool, int N, int G) {
    __shared__ int lpool[4][128];
    int tid = threadIdx.x;
    lpool[tid >> 7][tid & 127] = 0;
    lpool[(tid >> 7) + 2][tid & 127] = 0;
    __syncthreads();
    int lane = tid & 31;
    int p = lane >> 4;   // parity (edge subset)
    int s = lane & 15;   // h8 slot: feats s*8..s*8+7
    int blk_n0 = blockIdx.x * 16;
    int gfirst = batch[(blk_n0 < N) ? blk_n0 : (N - 1)];
    int n0 = blk_n0 + (tid >> 5) * 2;
    if (n0 < N) {
        int nA = n0;
        int nB = (n0 + 1 < N) ? n0 + 1 : n0;
        int2 rA = rse[nA];
        int2 rB = rse[nB];
        int cA0 = rA.x, cA1 = rA.y;
        int cB0 = rB.x, cB1 = rB.y;
        bool hasA = cA0 < cA1, hasB = cB0 < cB1;
        h8 sA = P8[(size_t)nA * 16 + s];
        h8 sB = P8[(size_t)nB * 16 + s];
        float aA[8] = {}, aB[8] = {};
        {
            h8 tA[8], tB[8];
            float wA[8], wB[8];
#pragma unroll
            for (int i = 0; i < 8; ++i) {
                int ei = cA0 + 2 * i + p;
                int ec = (ei < cA1) ? ei : (hasA ? cA1 - 1 : 0);
                tA[i] = P8[(size_t)(ed[ec].x & SRCMASK) * 16 + s];
                wA[i] = (ei < cA1) ? 1.f : 0.f;
            }
#pragma unroll
            for (int i = 0; i < 8; ++i) {
                int ei = cB0 + 2 * i + p;
                int ec = (ei < cB1) ? ei : (hasB ? cB1 - 1 : 0);
                tB[i] = P8[(size_t)(ed[ec].x & SRCMASK) * 16 + s];
                wB[i] = (ei < cB1) ? 1.f : 0.f;
            }
#pragma unroll
            for (int i = 0; i < 8; ++i)
#pragma unroll
                for (int f = 0; f < 8; ++f) aA[f] = fmaf(wA[i], (float)tA[i][f], aA[f]);
#pragma unroll
            for (int i = 0; i < 8; ++i)
#pragma unroll
                for (int f = 0; f < 8; ++f) aB[f] = fmaf(wB[i], (float)tB[i][f], aB[f]);
        }
        for (int eb = cA0 + 16; eb < cA1; eb += 16) {
            h8 t[8];
            float w[8];
#pragma unroll
            for (int i = 0; i < 8; ++i) {
                int ei = eb + 2 * i + p;
                int ec = (ei < cA1) ? ei : cA1 - 1;
                t[i] = P8[(size_t)(ed[ec].x & SRCMASK) * 16 + s];
                w[i] = (ei < cA1) ? 1.f : 0.f;
            }
#pragma unroll
            for (int i = 0; i < 8; ++i)
#pragma unroll
                for (int f = 0; f < 8; ++f) aA[f] = fmaf(w[i], (float)t[i][f], aA[f]);
        }
        for (int eb = cB0 + 16; eb < cB1; eb += 16) {
            h8 t[8];
            float w[8];
#pragma unroll
            for (int i = 0; i < 8; ++i) {
                int ei = eb + 2 * i + p;
                int ec = (ei < cB1) ? ei : cB1 - 1;
                t[i] = P8[(size_t)(ed[ec].x & SRCMASK) * 16 + s];
                w[i] = (ei < cB1) ? 1.f : 0.f;
            }
#pragma unroll
            for (int i = 0; i < 8; ++i)
#pragma unroll
                for (int f = 0; f < 8; ++f) aB[f] = fmaf(w[i], (float)t[i][f], aB[f]);
        }
        float dA = dinv[nA], dB = dinv[nB];
        int gA = batch[nA], gB = batch[nB];
        float4 bb0 = *(const float4*)&b2[s * 8];
        float4 bb1 = *(const float4*)&b2[s * 8 + 4];
        float bv[8] = {bb0.x, bb0.y, bb0.z, bb0.w, bb1.x, bb1.y, bb1.z, bb1.w};
        float zA[8], zB[8];
#pragma unroll
        for (int f = 0; f < 8; ++f) {
            float a = aA[f] + __shfl_xor(aA[f], 16);
            float b = aB[f] + __shfl_xor(aB[f], 16);
            zA[f] = fmaxf(fmaf(dA, (float)sA[f] + a, bv[f]), 0.f);
            zB[f] = fmaxf(fmaf(dB, (float)sB[f] + b, bv[f]), 0.f);
        }
        auto emit = [&](int g, const float* m) {
            if (p != 0) return;  // parities hold identical values post-reduce
            int slot = g - gfirst;
            if (slot < 4) {
#pragma unroll
                for (int f = 0; f < 8; ++f) {
                    int ff = (f + s) & 7;  // bank rotation
                    if (m[ff] > 0.f) atomicMax(&lpool[slot][s * 8 + ff], __float_as_int(m[ff]));
                }
            } else {
                float* pg = pool + (size_t)g * 128 + s * 8;
#pragma unroll
                for (int f = 0; f < 8; ++f)
                    if (m[f] > 0.f) atomicMax((int*)(pg + f), __float_as_int(m[f]));
            }
        };
        if (gA == gB) {
            float m[8];
#pragma unroll
            for (int f = 0; f < 8; ++f) m[f] = fmaxf(zA[f], zB[f]);
            emit(gA, m);
        } else {
            emit(gA, zA);
            emit(gB, zB);
        }
    }
    __syncthreads();
    {
        int f = tid & 127;
        for (int sl = tid >> 7; sl < 4; sl += 2) {
            int v = lpool[sl][f];
            if (v > 0) atomicMax((int*)&pool[(size_t)(gfirst + sl) * 128 + f], v);
        }
    }
}

// out[g][c] = blin[c] + sum_f pool[g][f] * Wlin[f][c]
__global__ __launch_bounds__(256) void k_final(const float* __restrict__ pool, const float* __restrict__ Wlin,
                                               const float* __restrict__ blin, float* __restrict__ out, int G) {
    int t = blockIdx.x * 256 + threadIdx.x;
    if (t >= G * 10) return;
    int g = t / 10, c = t % 10;
    float acc = blin[c];
    const float* pr = pool + (size_t)g * 128;
#pragma unroll 8
    for (int f = 0; f < 128; ++f) acc = fmaf(pr[f], Wlin[f * 10 + c], acc);
    out[t] = acc;
}

extern "C" void kernel_launch(void* const* d_in, const int* in_sizes, int n_in,
                              void* d_out, int out_size, void* d_ws, size_t ws_size,
                              hipStream_t stream) {
    const int* x = (const int*)d_in[0];
    const int* ei = (const int*)d_in[1];
    const int* batch = (const int*)d_in[2];
    const float* emb = (const float*)d_in[4];
    const float* W1 = (const float*)d_in[5];
    const float* b1 = (const float*)d_in[6];
    const float* W2 = (const float*)d_in[7];
    const float* b2 = (const float*)d_in[8];
    const float* Wlin = (const float*)d_in[9];
    const float* blin = (const float*)d_in[10];
    float* out = (float*)d_out;

    int N = in_sizes[0];
    int E = in_sizes[1] / 2;
    int VOCAB = in_sizes[4] / 64;
    int G = out_size / 10;
    const int* srcp = ei;
    const int* dstp = ei + E;

    char* p = (char*)d_ws;
    auto alloc = [&](size_t bytes) -> char* {
        char* r = p;
        p += (bytes + 255) & ~(size_t)255;
        return r;
    };
    int* deg = (int*)alloc((size_t)N * 4);
    int* exc = (int*)alloc((size_t)N * 4);
    int* cursor = (int*)alloc((size_t)N * 4);
    int2* rse = (int2*)alloc((size_t)N * 8);
    int* bsums = (int*)alloc(512 * 4);
    float* dinv = (float*)alloc((size_t)N * 4);
    int2* ed = (int2*)alloc((size_t)E * 8);
    _Float16* e16 = (_Float16*)alloc((size_t)VOCAB * 64 * 2);
    _Float16* W1T = (_Float16*)alloc(128 * 64 * 2);
    _Float16* W2T = (_Float16*)alloc(128 * 128 * 2);
    _Float16* P = (_Float16*)alloc((size_t)N * 128 * 2);
    float* pool = (float*)alloc((size_t)G * 128 * 4);

    int gE = (E + 255) / 256;
    int gN = (N + 255) / 256;  // 391 <= 512 (scan23 capacity)
    int nEmbF = VOCAB * 64;
    int nCast = (nEmbF / 4 + 255) / 256;
    int p4i = G * 128 / 4;

    k_zero<<<(N / 4 + 255) / 256, 256, 0, stream>>>((int4*)deg, N / 4);
    k_degprep<<<gE + nCast + 32 + 64, 256, 0, stream>>>(dstp, deg, E, emb, (__half2*)e16, W1, W1T,
                                                        W2, W2T, nEmbF, gE, nCast);
    k_scan1<<<gN, 256, 0, stream>>>(deg, exc, bsums, dinv, (int4*)pool, p4i, N);
    k_scan23<<<(N + 511) / 512, 512, 0, stream>>>(exc, bsums, cursor, rse, N, E, gN);
    k_fill<<<gE, 256, 0, stream>>>(srcp, dstp, x, dinv, cursor, ed, E);
    k_mlp<<<(N + 15) / 16, 256, 0, stream>>>((const __half2*)e16, x, dinv, rse, ed, W1T, b1,
                                             W2T, P, N);
    k_agg2pool<<<(N + 15) / 16, 256, 0, stream>>>((const h8*)P, batch, dinv, rse, ed,
                                                  b2, pool, N, G);
    k_final<<<(G * 10 + 255) / 256, 256, 0, stream>>>(pool, Wlin, blin, out, G);
}